// Round 6
// baseline (302.385 us; speedup 1.0000x reference)
//
#include <hip/hip_runtime.h>
#include <stdint.h>
#include <math.h>

typedef __attribute__((ext_vector_type(8))) short bf16x8;
typedef __attribute__((ext_vector_type(4))) short v4s;
typedef __attribute__((ext_vector_type(4))) float f32x4;
typedef __attribute__((ext_vector_type(4))) unsigned short u16x4;
typedef __attribute__((ext_vector_type(2))) unsigned int u32x2;

#define MFMA16(a,b,c)   __builtin_amdgcn_mfma_f32_16x16x32_bf16((a),(b),(c),0,0,0)
#define MFMA16K(a,b,c)  __builtin_amdgcn_mfma_f32_16x16x16bf16_1k((a),(b),(c),0,0,0)

static __device__ __forceinline__ void gld_lds16(const void* g, void* l) {
  __builtin_amdgcn_global_load_lds(
      (const __attribute__((address_space(1))) unsigned int*)g,
      (__attribute__((address_space(3))) unsigned int*)l,
      16, 0, 0);
}

static __device__ __forceinline__ unsigned short f2bf(float f) {
  unsigned int u = __builtin_bit_cast(unsigned int, f);
  return (unsigned short)((u + 0x8000u) >> 16);
}

// fp32 -> bf16, grid-stride, float4 loads.
__global__ __launch_bounds__(256) void cvt_kernel(const float* __restrict__ in,
                                                  unsigned short* __restrict__ out,
                                                  int n4) {
  int i = blockIdx.x * blockDim.x + threadIdx.x;
  int stride = gridDim.x * blockDim.x;
  for (; i < n4; i += stride) {
    float4 v = ((const float4*)in)[i];
    u16x4 o;
    o.x = f2bf(v.x); o.y = f2bf(v.y); o.z = f2bf(v.z); o.w = f2bf(v.w);
    ((u16x4*)out)[i] = o;
  }
}

__global__ __launch_bounds__(256) void cvt4_kernel(const float* __restrict__ w0,
                                                   const float* __restrict__ w1,
                                                   const float* __restrict__ w2,
                                                   const float* __restrict__ w3,
                                                   unsigned short* __restrict__ out) {
  const float* in = (blockIdx.y == 0) ? w0 : (blockIdx.y == 1) ? w1
                  : (blockIdx.y == 2) ? w2 : w3;
  unsigned short* o = out + (size_t)blockIdx.y * 1048576;
  int i = blockIdx.x * blockDim.x + threadIdx.x;
  int stride = gridDim.x * blockDim.x;
  for (; i < 1048576/4; i += stride) {
    float4 v = ((const float4*)in)[i];
    u16x4 t;
    t.x = f2bf(v.x); t.y = f2bf(v.y); t.z = f2bf(v.z); t.w = f2bf(v.w);
    ((u16x4*)o)[i] = t;
  }
}

// C = A[M,K] * Bt[N,K]^T, A/Bt bf16, K=1024, 128x128 tile.
// MODE 0: C bf16 head-split [b,h,s,d] (b=row>>11).
// MODE 1: C fp32 row-major [M,1024].
// MODE 2: C bf16 head-split TRANSPOSED [b,h,d,s] (for V).
// MODE 3: like MODE 0 but scaled by log2(e)/8 (for Q: folds softmax scale).
template<int MODE, typename CT>
__device__ __forceinline__ void gemm_bt_tile(const unsigned short* __restrict__ A,
                                             const unsigned short* __restrict__ Bt,
                                             CT* __restrict__ C,
                                             int m0, int n0)
{
  __shared__ __align__(16) unsigned short As[128*32];
  __shared__ __align__(16) unsigned short Bs[128*32];
  const int tid  = threadIdx.x;
  const int w    = tid >> 6, lane = tid & 63;
  const int quad = lane >> 4, c0 = lane & 15;
  const int wm   = w >> 1, wn = w & 1;

  const unsigned short* ga[2];
  const unsigned short* gb[2];
  int ldsoff[2];
  #pragma unroll
  for (int i = 0; i < 2; ++i) {
    int f = i*4096 + w*1024 + lane*16;   // byte offset in 8KB tile
    int r = f >> 6;                      // tile row (64B = 32 bf16 per row)
    int q = (f >> 4) & 3;                // 16B chunk in row
    ga[i] = A  + (m0 + r)*1024 + q*8;
    gb[i] = Bt + (n0 + r)*1024 + q*8;
    ldsoff[i] = i*4096 + w*1024;
  }

  int aAddr[4], bAddr[4];
  #pragma unroll
  for (int t = 0; t < 4; ++t) {
    aAddr[t] = (wm*64 + t*16 + c0)*64 + quad*16;
    bAddr[t] = (wn*64 + t*16 + c0)*64 + quad*16;
  }

  f32x4 acc[4][4];
  #pragma unroll
  for (int i = 0; i < 4; ++i)
    #pragma unroll
    for (int j = 0; j < 4; ++j)
      acc[i][j] = (f32x4){0.f, 0.f, 0.f, 0.f};

  for (int kt = 0; kt < 32; ++kt) {
    __syncthreads();
    #pragma unroll
    for (int i = 0; i < 2; ++i) {
      gld_lds16(ga[i] + kt*32, (char*)As + ldsoff[i]);
      gld_lds16(gb[i] + kt*32, (char*)Bs + ldsoff[i]);
    }
    __syncthreads();

    bf16x8 af[4], bfr[4];
    #pragma unroll
    for (int t = 0; t < 4; ++t) af[t]  = *(const bf16x8*)((const char*)As + aAddr[t]);
    #pragma unroll
    for (int t = 0; t < 4; ++t) bfr[t] = *(const bf16x8*)((const char*)Bs + bAddr[t]);

    #pragma unroll
    for (int mt = 0; mt < 4; ++mt)
      #pragma unroll
      for (int nt = 0; nt < 4; ++nt)
        acc[mt][nt] = MFMA16(af[mt], bfr[nt], acc[mt][nt]);
  }

  const float scl = (MODE == 3) ? 0.1803368801f : 1.0f;  // log2(e)/8
  #pragma unroll
  for (int mt = 0; mt < 4; ++mt) {
    #pragma unroll
    for (int nt = 0; nt < 4; ++nt) {
      if (MODE == 2) {
        u16x4 pk;
        #pragma unroll
        for (int r = 0; r < 4; ++r) pk[r] = f2bf(acc[mt][nt][r]);
        int s0 = m0 + wm*64 + mt*16 + quad*4;
        int gc = n0 + wn*64 + nt*16 + c0;
        int b = s0 >> 11, ss = s0 & 2047;
        int h = gc >> 6, d = gc & 63;
        *(u16x4*)((unsigned short*)C + (size_t)(((b << 4) + h)*64 + d)*2048 + ss) = pk;
      } else {
        #pragma unroll
        for (int r = 0; r < 4; ++r) {
          int gr = m0 + wm*64 + mt*16 + quad*4 + r;
          int gc = n0 + wn*64 + nt*16 + c0;
          if (MODE == 0 || MODE == 3) {
            int b = gr >> 11, s = gr & 2047;
            int h = gc >> 6, d = gc & 63;
            ((unsigned short*)C)[(((b << 4) + h)*2048 + s)*64 + d] = f2bf(acc[mt][nt][r] * scl);
          } else {
            ((float*)C)[gr*1024 + gc] = acc[mt][nt][r];
          }
        }
      }
    }
  }
}

__global__ __launch_bounds__(256) void qkv_kernel(
    const unsigned short* __restrict__ X,
    const unsigned short* __restrict__ WQ, const unsigned short* __restrict__ WK,
    const unsigned short* __restrict__ WV,
    unsigned short* __restrict__ Q, unsigned short* __restrict__ K,
    unsigned short* __restrict__ V)
{
  if (blockIdx.z == 2) {
    gemm_bt_tile<2>(X, WV, V, blockIdx.x*128, blockIdx.y*128);
  } else if (blockIdx.z == 0) {
    gemm_bt_tile<3>(X, WQ, Q, blockIdx.x*128, blockIdx.y*128);  // pre-scaled Q
  } else {
    gemm_bt_tile<0>(X, WK, K, blockIdx.x*128, blockIdx.y*128);
  }
}

__global__ __launch_bounds__(256) void proj_kernel(
    const unsigned short* __restrict__ A,
    const unsigned short* __restrict__ WO,
    float* __restrict__ C)
{
  gemm_bt_tile<1>(A, WO, C, blockIdx.x*128, blockIdx.y*128);
}

// Flash attention, causal. Q (pre-scaled by log2e/8) / K bf16 [bh,s,64];
// V TRANSPOSED bf16 [bh,64,s]. O bf16 [b,s,1024].
// Grid (BH, 16), ONE q-tile per block: 1024 blocks -> 4 blocks/CU resident
// (round-3's 512-block paired grid capped residency at 2 blocks/CU; that grid
// was the occupancy limiter, not registers: VGPR 120 <= 128 allows 4 waves/SIMD,
// LDS 32KB allows 5 blocks).
// __launch_bounds__(256,2) is kept EXACTLY as round 3: demanding more
// (256,4) forces the allocator to a ~64-VGPR budget and ~180MB of scratch
// spill (measured twice, r1/r4). Grid growth alone must not change regalloc.
// qt = magic-square permutation of blockIdx.y (nibbles of 0xf4831a6d295ec7b0):
// both consecutive-4 and stride-4 y-groups have equal total work -> balanced
// under either block->CU assignment. XCD locality: linear id = bh + BH*y ->
// XCD = bh%8 for any y: all 16 blocks of one head share one XCD's L2
// (round-3 win: FETCH 143->31MB).
// S^T = K Q^T in-register P (16x16x16 PV), tail K-tile register prefetch
// (r5 showed in-body prefetch adds VGPR pressure -> mild spill -> slower),
// V^T double-buffered via global_load_lds, one barrier per tile.
__global__ __launch_bounds__(256, 2) void attn_kernel(
    const unsigned short* __restrict__ Q,
    const unsigned short* __restrict__ K,
    const unsigned short* __restrict__ Vt,
    unsigned short* __restrict__ O)
{
  __shared__ __align__(16) unsigned short VtL[2][64*128];  // V^T tiles, chunk-swizzled

  const int tid  = threadIdx.x;
  const int w    = tid >> 6, lane = tid & 63;
  const int quad = lane >> 4, c0 = lane & 15;
  const int bh = blockIdx.x;
  const int qt = (int)((0xf4831a6d295ec7b0ull >> (4*blockIdx.y)) & 15ull);

  const unsigned short* Qh = Q  + (size_t)bh*2048*64;
  const unsigned short* Kh = K  + (size_t)bh*2048*64;
  const unsigned short* Vh = Vt + (size_t)bh*64*2048;

  // V^T staging: LDS chunk (row r, chunk q) receives global chunk q^(r&15)
  const unsigned short* vga[4];
  int vldsoff[4];
  #pragma unroll
  for (int i = 0; i < 4; ++i) {
    int cid = i*256 + tid;
    int r = cid >> 4, q = cid & 15;
    int gq = q ^ (r & 15);
    vga[i] = Vh + (size_t)r*2048 + gq*8;
    vldsoff[i] = i*4096 + w*1024;
  }

  const int b = bh >> 4, h = bh & 15;
  bf16x8 kreg[8][2];   // current K tile in registers

  #define ATTN_MK_BODY(mk, Vb, DIAG)                                              \
  {                                                                               \
    f32x4 s0 = (f32x4){0.f,0.f,0.f,0.f}, s1 = (f32x4){0.f,0.f,0.f,0.f};           \
    _Pragma("unroll")                                                             \
    for (int ks = 0; ks < 2; ++ks) {                                              \
      s0 = MFMA16(kreg[mk][ks], qf[0][ks], s0);                                   \
      s1 = MFMA16(kreg[mk][ks], qf[1][ks], s1);                                   \
    }                                                                             \
    if (DIAG) {                                                                   \
      _Pragma("unroll")                                                           \
      for (int r = 0; r < 4; ++r) {                                               \
        int kk = (mk)*16 + quad*4 + r;                                            \
        if (kk > w*32 + c0)      s0[r] = -1e30f;                                  \
        if (kk > w*32 + 16 + c0) s1[r] = -1e30f;                                  \
      }                                                                           \
    }                                                                             \
    float p00 = __builtin_amdgcn_exp2f(s0[0]), p01 = __builtin_amdgcn_exp2f(s0[1]); \
    float p02 = __builtin_amdgcn_exp2f(s0[2]), p03 = __builtin_amdgcn_exp2f(s0[3]); \
    float p10 = __builtin_amdgcn_exp2f(s1[0]), p11 = __builtin_amdgcn_exp2f(s1[1]); \
    float p12 = __builtin_amdgcn_exp2f(s1[2]), p13 = __builtin_amdgcn_exp2f(s1[3]); \
    l_r[0] += (p00 + p01) + (p02 + p03);                                          \
    l_r[1] += (p10 + p11) + (p12 + p13);                                          \
    u32x2 a0, a1;                                                                 \
    a0.x = __builtin_amdgcn_perm(__builtin_bit_cast(unsigned int, p01),           \
                                 __builtin_bit_cast(unsigned int, p00), 0x07060302u); \
    a0.y = __builtin_amdgcn_perm(__builtin_bit_cast(unsigned int, p03),           \
                                 __builtin_bit_cast(unsigned int, p02), 0x07060302u); \
    a1.x = __builtin_amdgcn_perm(__builtin_bit_cast(unsigned int, p11),           \
                                 __builtin_bit_cast(unsigned int, p10), 0x07060302u); \
    a1.y = __builtin_amdgcn_perm(__builtin_bit_cast(unsigned int, p13),           \
                                 __builtin_bit_cast(unsigned int, p12), 0x07060302u); \
    v4s pa0 = __builtin_bit_cast(v4s, a0);                                        \
    v4s pa1 = __builtin_bit_cast(v4s, a1);                                        \
    _Pragma("unroll")                                                             \
    for (int dt = 0; dt < 4; ++dt) {                                              \
      int vr = dt*16 + c0;                                                        \
      int p  = 2*(mk) + (quad >> 1);                                              \
      v4s vb = *(const v4s*)((const char*)(Vb) + vr*256 + ((p ^ c0) * 16) + (quad & 1)*8); \
      o_[0][dt] = MFMA16K(pa0, vb, o_[0][dt]);                                    \
      o_[1][dt] = MFMA16K(pa1, vb, o_[1][dt]);                                    \
    }                                                                             \
  }

  {
    // Q B-frags: B[n=q=c0][k=d=quad*8+j]
    bf16x8 qf[2][2];
    #pragma unroll
    for (int mq = 0; mq < 2; ++mq)
      #pragma unroll
      for (int ks = 0; ks < 2; ++ks)
        qf[mq][ks] = *(const bf16x8*)(Qh + (qt*128 + w*32 + mq*16 + c0)*64 + ks*32 + quad*8);

    f32x4 o_[2][4];
    float l_r[2] = {0.f, 0.f};
    #pragma unroll
    for (int mq = 0; mq < 2; ++mq)
      #pragma unroll
      for (int dt = 0; dt < 4; ++dt) o_[mq][dt] = (f32x4){0.f, 0.f, 0.f, 0.f};

    #pragma unroll
    for (int i = 0; i < 4; ++i)
      gld_lds16(vga[i], (char*)VtL[0] + vldsoff[i]);
    #pragma unroll
    for (int mk = 0; mk < 8; ++mk)
      #pragma unroll
      for (int ks = 0; ks < 2; ++ks)
        kreg[mk][ks] = *(const bf16x8*)(Kh + (mk*16 + c0)*64 + ks*32 + quad*8);

    for (int kt = 0; kt < qt; ++kt) {
      __syncthreads();   // drains V DMA for kt + K prefetch; readers of buf[(kt+1)&1] done
      #pragma unroll
      for (int i = 0; i < 4; ++i)
        gld_lds16(vga[i] + (kt+1)*128, (char*)VtL[(kt+1)&1] + vldsoff[i]);
      const unsigned short* Vb = VtL[kt & 1];
      #pragma unroll
      for (int mk = 0; mk < 8; ++mk)
        ATTN_MK_BODY(mk, Vb, false)
      // prefetch next K tile into registers (drained by next barrier)
      #pragma unroll
      for (int mk = 0; mk < 8; ++mk)
        #pragma unroll
        for (int ks = 0; ks < 2; ++ks)
          kreg[mk][ks] = *(const bf16x8*)(Kh + ((kt+1)*128 + mk*16 + c0)*64 + ks*32 + quad*8);
    }

    // diagonal tile: mask; skip fully-masked k-blocks (wave w needs mk < 2w+2)
    {
      __syncthreads();
      const unsigned short* Vb = VtL[qt & 1];
      #pragma unroll
      for (int mk = 0; mk < 8; ++mk)
        if (mk < 2*w + 2)
          ATTN_MK_BODY(mk, Vb, true)
    }

    // reduce l across quads; epilogue
    #pragma unroll
    for (int mq = 0; mq < 2; ++mq) {
      l_r[mq] += __shfl_xor(l_r[mq], 16);
      l_r[mq] += __shfl_xor(l_r[mq], 32);
    }
    #pragma unroll
    for (int mt = 0; mt < 2; ++mt) {
      #pragma unroll
      for (int r = 0; r < 4; ++r) {
        float l = __shfl(l_r[mt], quad*4 + r);
        float inv = 1.0f / l;
        int srow = qt*128 + w*32 + mt*16 + quad*4 + r;
        #pragma unroll
        for (int dt = 0; dt < 4; ++dt) {
          int col = h*64 + dt*16 + c0;
          O[((size_t)b*2048 + srow)*1024 + col] = f2bf(o_[mt][dt][r] * inv);
        }
      }
    }
  }
  #undef ATTN_MK_BODY
}

extern "C" void kernel_launch(void* const* d_in, const int* in_sizes, int n_in,
                              void* d_out, int out_size, void* d_ws, size_t ws_size,
                              hipStream_t stream) {
  const float* xf  = (const float*)d_in[0];
  const float* wqf = (const float*)d_in[1];
  const float* wkf = (const float*)d_in[2];
  const float* wvf = (const float*)d_in[3];
  const float* wof = (const float*)d_in[4];
  float* out = (float*)d_out;
  unsigned short* ws = (unsigned short*)d_ws;

  const bool fused = ws_size >= (size_t)58720256;  // 56 MB

  if (fused) {
    unsigned short* xb  = ws;                    // 8M elems; aliased by Ow after qkv
    unsigned short* wb  = ws + 8388608;          // wq|wk|wv|wo, 1M each
    unsigned short* Kw  = ws + 12582912;
    unsigned short* Vw  = ws + 20971520;
    unsigned short* Ow  = xb;
    unsigned short* Qd  = (unsigned short*)out;  // bf16 Q scratch in fp32 out region

    cvt_kernel <<<2048, 256, 0, stream>>>(xf, xb, 8388608/4);
    cvt4_kernel<<<dim3(256, 4), 256, 0, stream>>>(wqf, wkf, wvf, wof, wb);

    qkv_kernel <<<dim3(64, 8, 3), 256, 0, stream>>>(xb, wb, wb + 1048576, wb + 2097152,
                                                    Qd, Kw, Vw);
    attn_kernel<<<dim3(64, 16),   256, 0, stream>>>(Qd, Kw, Vw, Ow);
    proj_kernel<<<dim3(64, 8),    256, 0, stream>>>(Ow, wb + 3145728, out);
  } else {
    unsigned short* xb  = ws;
    unsigned short* wb  = ws + 8388608;
    unsigned short* Kw  = ws + 12582912;
    unsigned short* Vw  = ws + 14680064;
    unsigned short* Ow  = ws + 16777216;

    cvt_kernel <<<2048, 256, 0, stream>>>(xf, xb, 8388608/4);
    cvt4_kernel<<<dim3(256, 4), 256, 0, stream>>>(wqf, wkf, wvf, wof, wb);

    for (int b = 0; b < 4; ++b) {
      const unsigned short* xbb = xb  + (size_t)b * 2048 * 1024;
      float*               outb = out + (size_t)b * 2048 * 1024;
      unsigned short*        Qd = (unsigned short*)outb;
      qkv_kernel <<<dim3(16, 8, 3), 256, 0, stream>>>(xbb, wb, wb + 1048576, wb + 2097152,
                                                      Qd, Kw, Vw);
      attn_kernel<<<dim3(16, 16),   256, 0, stream>>>(Qd, Kw, Vw, Ow);
      proj_kernel<<<dim3(16, 8),    256, 0, stream>>>(Ow, wb + 3145728, outb);
    }
  }
}

// Round 7
// 237.807 us; speedup vs baseline: 1.2716x; 1.2716x over previous
//
#include <hip/hip_runtime.h>
#include <stdint.h>
#include <math.h>

typedef __attribute__((ext_vector_type(8))) short bf16x8;
typedef __attribute__((ext_vector_type(4))) short v4s;
typedef __attribute__((ext_vector_type(4))) float f32x4;
typedef __attribute__((ext_vector_type(4))) unsigned short u16x4;
typedef __attribute__((ext_vector_type(2))) unsigned int u32x2;

#define MFMA16(a,b,c)   __builtin_amdgcn_mfma_f32_16x16x32_bf16((a),(b),(c),0,0,0)
#define MFMA16K(a,b,c)  __builtin_amdgcn_mfma_f32_16x16x16bf16_1k((a),(b),(c),0,0,0)

static __device__ __forceinline__ void gld_lds16(const void* g, void* l) {
  __builtin_amdgcn_global_load_lds(
      (const __attribute__((address_space(1))) unsigned int*)g,
      (__attribute__((address_space(3))) unsigned int*)l,
      16, 0, 0);
}

static __device__ __forceinline__ unsigned short f2bf(float f) {
  unsigned int u = __builtin_bit_cast(unsigned int, f);
  return (unsigned short)((u + 0x8000u) >> 16);
}

// fp32 -> bf16, grid-stride, float4 loads.
__global__ __launch_bounds__(256) void cvt_kernel(const float* __restrict__ in,
                                                  unsigned short* __restrict__ out,
                                                  int n4) {
  int i = blockIdx.x * blockDim.x + threadIdx.x;
  int stride = gridDim.x * blockDim.x;
  for (; i < n4; i += stride) {
    float4 v = ((const float4*)in)[i];
    u16x4 o;
    o.x = f2bf(v.x); o.y = f2bf(v.y); o.z = f2bf(v.z); o.w = f2bf(v.w);
    ((u16x4*)out)[i] = o;
  }
}

__global__ __launch_bounds__(256) void cvt4_kernel(const float* __restrict__ w0,
                                                   const float* __restrict__ w1,
                                                   const float* __restrict__ w2,
                                                   const float* __restrict__ w3,
                                                   unsigned short* __restrict__ out) {
  const float* in = (blockIdx.y == 0) ? w0 : (blockIdx.y == 1) ? w1
                  : (blockIdx.y == 2) ? w2 : w3;
  unsigned short* o = out + (size_t)blockIdx.y * 1048576;
  int i = blockIdx.x * blockDim.x + threadIdx.x;
  int stride = gridDim.x * blockDim.x;
  for (; i < 1048576/4; i += stride) {
    float4 v = ((const float4*)in)[i];
    u16x4 t;
    t.x = f2bf(v.x); t.y = f2bf(v.y); t.z = f2bf(v.z); t.w = f2bf(v.w);
    ((u16x4*)o)[i] = t;
  }
}

// C = A[M,K] * Bt[N,K]^T, A/Bt bf16, K=1024, 128x128 tile.
// MODE 0: C bf16 head-split [b,h,s,d] (b=row>>11).
// MODE 1: C fp32 row-major [M,1024].
// MODE 2: C bf16 head-split TRANSPOSED [b,h,d,s] (for V).
// MODE 3: like MODE 0 but scaled by log2(e)/8 (for Q: folds softmax scale).
template<int MODE, typename CT>
__device__ __forceinline__ void gemm_bt_tile(const unsigned short* __restrict__ A,
                                             const unsigned short* __restrict__ Bt,
                                             CT* __restrict__ C,
                                             int m0, int n0)
{
  __shared__ __align__(16) unsigned short As[128*32];
  __shared__ __align__(16) unsigned short Bs[128*32];
  const int tid  = threadIdx.x;
  const int w    = tid >> 6, lane = tid & 63;
  const int quad = lane >> 4, c0 = lane & 15;
  const int wm   = w >> 1, wn = w & 1;

  const unsigned short* ga[2];
  const unsigned short* gb[2];
  int ldsoff[2];
  #pragma unroll
  for (int i = 0; i < 2; ++i) {
    int f = i*4096 + w*1024 + lane*16;   // byte offset in 8KB tile
    int r = f >> 6;                      // tile row (64B = 32 bf16 per row)
    int q = (f >> 4) & 3;                // 16B chunk in row
    ga[i] = A  + (m0 + r)*1024 + q*8;
    gb[i] = Bt + (n0 + r)*1024 + q*8;
    ldsoff[i] = i*4096 + w*1024;
  }

  int aAddr[4], bAddr[4];
  #pragma unroll
  for (int t = 0; t < 4; ++t) {
    aAddr[t] = (wm*64 + t*16 + c0)*64 + quad*16;
    bAddr[t] = (wn*64 + t*16 + c0)*64 + quad*16;
  }

  f32x4 acc[4][4];
  #pragma unroll
  for (int i = 0; i < 4; ++i)
    #pragma unroll
    for (int j = 0; j < 4; ++j)
      acc[i][j] = (f32x4){0.f, 0.f, 0.f, 0.f};

  for (int kt = 0; kt < 32; ++kt) {
    __syncthreads();
    #pragma unroll
    for (int i = 0; i < 2; ++i) {
      gld_lds16(ga[i] + kt*32, (char*)As + ldsoff[i]);
      gld_lds16(gb[i] + kt*32, (char*)Bs + ldsoff[i]);
    }
    __syncthreads();

    bf16x8 af[4], bfr[4];
    #pragma unroll
    for (int t = 0; t < 4; ++t) af[t]  = *(const bf16x8*)((const char*)As + aAddr[t]);
    #pragma unroll
    for (int t = 0; t < 4; ++t) bfr[t] = *(const bf16x8*)((const char*)Bs + bAddr[t]);

    #pragma unroll
    for (int mt = 0; mt < 4; ++mt)
      #pragma unroll
      for (int nt = 0; nt < 4; ++nt)
        acc[mt][nt] = MFMA16(af[mt], bfr[nt], acc[mt][nt]);
  }

  const float scl = (MODE == 3) ? 0.1803368801f : 1.0f;  // log2(e)/8
  #pragma unroll
  for (int mt = 0; mt < 4; ++mt) {
    #pragma unroll
    for (int nt = 0; nt < 4; ++nt) {
      if (MODE == 2) {
        u16x4 pk;
        #pragma unroll
        for (int r = 0; r < 4; ++r) pk[r] = f2bf(acc[mt][nt][r]);
        int s0 = m0 + wm*64 + mt*16 + quad*4;
        int gc = n0 + wn*64 + nt*16 + c0;
        int b = s0 >> 11, ss = s0 & 2047;
        int h = gc >> 6, d = gc & 63;
        *(u16x4*)((unsigned short*)C + (size_t)(((b << 4) + h)*64 + d)*2048 + ss) = pk;
      } else {
        #pragma unroll
        for (int r = 0; r < 4; ++r) {
          int gr = m0 + wm*64 + mt*16 + quad*4 + r;
          int gc = n0 + wn*64 + nt*16 + c0;
          if (MODE == 0 || MODE == 3) {
            int b = gr >> 11, s = gr & 2047;
            int h = gc >> 6, d = gc & 63;
            ((unsigned short*)C)[(((b << 4) + h)*2048 + s)*64 + d] = f2bf(acc[mt][nt][r] * scl);
          } else {
            ((float*)C)[gr*1024 + gc] = acc[mt][nt][r];
          }
        }
      }
    }
  }
}

__global__ __launch_bounds__(256) void qkv_kernel(
    const unsigned short* __restrict__ X,
    const unsigned short* __restrict__ WQ, const unsigned short* __restrict__ WK,
    const unsigned short* __restrict__ WV,
    unsigned short* __restrict__ Q, unsigned short* __restrict__ K,
    unsigned short* __restrict__ V)
{
  if (blockIdx.z == 2) {
    gemm_bt_tile<2>(X, WV, V, blockIdx.x*128, blockIdx.y*128);
  } else if (blockIdx.z == 0) {
    gemm_bt_tile<3>(X, WQ, Q, blockIdx.x*128, blockIdx.y*128);  // pre-scaled Q
  } else {
    gemm_bt_tile<0>(X, WK, K, blockIdx.x*128, blockIdx.y*128);
  }
}

__global__ __launch_bounds__(256) void proj_kernel(
    const unsigned short* __restrict__ A,
    const unsigned short* __restrict__ WO,
    float* __restrict__ C)
{
  gemm_bt_tile<1>(A, WO, C, blockIdx.x*128, blockIdx.y*128);
}

// Flash attention, causal. Q (pre-scaled by log2e/8) / K bf16 [bh,s,64];
// V TRANSPOSED bf16 [bh,64,s]. O bf16 [b,s,1024].
// Grid (BH, 8): block y processes the qt-PAIR {15-by, by} = 17 K-tiles ->
// equal-length blocks (r6 showed unequal blocks create a dispatch tail).
// Linear id = bh + BH*y -> XCD = bh%8: all 8 blocks of one head share one
// XCD's L2 (r3 win: FETCH 143->31MB).
// __launch_bounds__(256,2): 2 waves/SIMD is the ceiling for this footprint
// ((.,4) forced 64-VGPR + ~180MB spill twice: r1, r4).
// NEW vs r3: K staged through LDS like V (double-buffered, global_load_lds
// issued at tile START -> full tile of compute covers the DMA before the
// barrier drains vmcnt; r3 issued 16 global K-loads at tile END, exposing a
// full L2 round-trip every tile). Source-side XOR swizzle (chunk ^= row&7,
// linear LDS dest) makes the per-body ds_read_b128 K reads bank-conflict-free.
// Deletes kreg[8][2] (64 VGPRs live across the tile) -> pressure DROPS.
// s_setprio(1) around each tile's MFMA+softmax cluster (T5; attn blocks are
// independent per CU -> priority arbitration has something to do).
__global__ __launch_bounds__(256, 2) void attn_kernel(
    const unsigned short* __restrict__ Q,
    const unsigned short* __restrict__ K,
    const unsigned short* __restrict__ Vt,
    unsigned short* __restrict__ O)
{
  __shared__ __align__(16) unsigned short VtL[2][64*128];  // V^T tiles, chunk-swizzled
  __shared__ __align__(16) unsigned short KL[2][128*64];   // K tiles, chunk-swizzled

  const int tid  = threadIdx.x;
  const int w    = tid >> 6, lane = tid & 63;
  const int quad = lane >> 4, c0 = lane & 15;
  const int bx = blockIdx.y, bh = blockIdx.x;

  const unsigned short* Qh = Q  + (size_t)bh*2048*64;
  const unsigned short* Kh = K  + (size_t)bh*2048*64;
  const unsigned short* Vh = Vt + (size_t)bh*64*2048;

  // V^T staging: LDS chunk (row r, chunk q) receives global chunk q^(r&15)
  const unsigned short* vga[4];
  // K staging: row r (128B = 8 chunks), LDS chunk (r, q) <- global chunk q^(r&7)
  const unsigned short* kga[4];
  int ldso[4];
  #pragma unroll
  for (int i = 0; i < 4; ++i) {
    int cid = i*256 + tid;
    int vr = cid >> 4, vq = cid & 15;
    vga[i] = Vh + (size_t)vr*2048 + (vq ^ (vr & 15))*8;
    int kr = cid >> 3, kq = cid & 7;
    kga[i] = Kh + (size_t)kr*64 + (kq ^ (kr & 7))*8;
    ldso[i] = i*4096 + w*1024;     // linear dest, byte = cid*16
  }

  const int b = bh >> 4, h = bh & 15;

  #define ATTN_MK_BODY(mk, Kb, Vb, DIAG)                                          \
  {                                                                               \
    bf16x8 ka0 = *(const bf16x8*)((const char*)(Kb) + ((mk)*16 + c0)*128          \
                                  + (((0*4 + quad) ^ (c0 & 7)) * 16));            \
    bf16x8 ka1 = *(const bf16x8*)((const char*)(Kb) + ((mk)*16 + c0)*128          \
                                  + (((1*4 + quad) ^ (c0 & 7)) * 16));            \
    f32x4 s0 = (f32x4){0.f,0.f,0.f,0.f}, s1 = (f32x4){0.f,0.f,0.f,0.f};           \
    s0 = MFMA16(ka0, qf[0][0], s0);                                               \
    s1 = MFMA16(ka0, qf[1][0], s1);                                               \
    s0 = MFMA16(ka1, qf[0][1], s0);                                               \
    s1 = MFMA16(ka1, qf[1][1], s1);                                               \
    if (DIAG) {                                                                   \
      _Pragma("unroll")                                                           \
      for (int r = 0; r < 4; ++r) {                                               \
        int kk = (mk)*16 + quad*4 + r;                                            \
        if (kk > w*32 + c0)      s0[r] = -1e30f;                                  \
        if (kk > w*32 + 16 + c0) s1[r] = -1e30f;                                  \
      }                                                                           \
    }                                                                             \
    float p00 = __builtin_amdgcn_exp2f(s0[0]), p01 = __builtin_amdgcn_exp2f(s0[1]); \
    float p02 = __builtin_amdgcn_exp2f(s0[2]), p03 = __builtin_amdgcn_exp2f(s0[3]); \
    float p10 = __builtin_amdgcn_exp2f(s1[0]), p11 = __builtin_amdgcn_exp2f(s1[1]); \
    float p12 = __builtin_amdgcn_exp2f(s1[2]), p13 = __builtin_amdgcn_exp2f(s1[3]); \
    l_r[0] += (p00 + p01) + (p02 + p03);                                          \
    l_r[1] += (p10 + p11) + (p12 + p13);                                          \
    u32x2 a0, a1;                                                                 \
    a0.x = __builtin_amdgcn_perm(__builtin_bit_cast(unsigned int, p01),           \
                                 __builtin_bit_cast(unsigned int, p00), 0x07060302u); \
    a0.y = __builtin_amdgcn_perm(__builtin_bit_cast(unsigned int, p03),           \
                                 __builtin_bit_cast(unsigned int, p02), 0x07060302u); \
    a1.x = __builtin_amdgcn_perm(__builtin_bit_cast(unsigned int, p11),           \
                                 __builtin_bit_cast(unsigned int, p10), 0x07060302u); \
    a1.y = __builtin_amdgcn_perm(__builtin_bit_cast(unsigned int, p13),           \
                                 __builtin_bit_cast(unsigned int, p12), 0x07060302u); \
    v4s pa0 = __builtin_bit_cast(v4s, a0);                                        \
    v4s pa1 = __builtin_bit_cast(v4s, a1);                                        \
    _Pragma("unroll")                                                             \
    for (int dt = 0; dt < 4; ++dt) {                                              \
      int vr = dt*16 + c0;                                                        \
      int p  = 2*(mk) + (quad >> 1);                                              \
      v4s vb = *(const v4s*)((const char*)(Vb) + vr*256 + ((p ^ c0) * 16) + (quad & 1)*8); \
      o_[0][dt] = MFMA16K(pa0, vb, o_[0][dt]);                                    \
      o_[1][dt] = MFMA16K(pa1, vb, o_[1][dt]);                                    \
    }                                                                             \
  }

  for (int pi = 0; pi < 2; ++pi) {
    const int qt = pi ? bx : 15 - bx;

    // Q B-frags: B[n=q=c0][k=d=quad*8+j]
    bf16x8 qf[2][2];
    #pragma unroll
    for (int mq = 0; mq < 2; ++mq)
      #pragma unroll
      for (int ks = 0; ks < 2; ++ks)
        qf[mq][ks] = *(const bf16x8*)(Qh + (qt*128 + w*32 + mq*16 + c0)*64 + ks*32 + quad*8);

    f32x4 o_[2][4];
    float l_r[2] = {0.f, 0.f};
    #pragma unroll
    for (int mq = 0; mq < 2; ++mq)
      #pragma unroll
      for (int dt = 0; dt < 4; ++dt) o_[mq][dt] = (f32x4){0.f, 0.f, 0.f, 0.f};

    __syncthreads();   // prior pass's LDS readers done
    #pragma unroll
    for (int i = 0; i < 4; ++i) {
      gld_lds16(vga[i], (char*)VtL[0] + ldso[i]);
      gld_lds16(kga[i], (char*)KL[0]  + ldso[i]);
    }

    for (int kt = 0; kt < qt; ++kt) {
      __syncthreads();   // drains V+K DMA for kt; readers of buf[(kt+1)&1] done
      #pragma unroll
      for (int i = 0; i < 4; ++i) {
        gld_lds16(vga[i] + (kt+1)*128,  (char*)VtL[(kt+1)&1] + ldso[i]);
        gld_lds16(kga[i] + (kt+1)*8192, (char*)KL[(kt+1)&1]  + ldso[i]);
      }
      const unsigned short* Vb = VtL[kt & 1];
      const unsigned short* Kb = KL[kt & 1];
      __builtin_amdgcn_s_setprio(1);
      #pragma unroll
      for (int mk = 0; mk < 8; ++mk)
        ATTN_MK_BODY(mk, Kb, Vb, false)
      __builtin_amdgcn_s_setprio(0);
    }

    // diagonal tile: mask; skip fully-masked k-blocks (wave w needs mk < 2w+2)
    {
      __syncthreads();
      const unsigned short* Vb = VtL[qt & 1];
      const unsigned short* Kb = KL[qt & 1];
      __builtin_amdgcn_s_setprio(1);
      #pragma unroll
      for (int mk = 0; mk < 8; ++mk)
        if (mk < 2*w + 2)
          ATTN_MK_BODY(mk, Kb, Vb, true)
      __builtin_amdgcn_s_setprio(0);
    }

    // reduce l across quads; epilogue
    #pragma unroll
    for (int mq = 0; mq < 2; ++mq) {
      l_r[mq] += __shfl_xor(l_r[mq], 16);
      l_r[mq] += __shfl_xor(l_r[mq], 32);
    }
    #pragma unroll
    for (int mt = 0; mt < 2; ++mt) {
      #pragma unroll
      for (int r = 0; r < 4; ++r) {
        float l = __shfl(l_r[mt], quad*4 + r);
        float inv = 1.0f / l;
        int srow = qt*128 + w*32 + mt*16 + quad*4 + r;
        #pragma unroll
        for (int dt = 0; dt < 4; ++dt) {
          int col = h*64 + dt*16 + c0;
          O[((size_t)b*2048 + srow)*1024 + col] = f2bf(o_[mt][dt][r] * inv);
        }
      }
    }
  }
  #undef ATTN_MK_BODY
}

extern "C" void kernel_launch(void* const* d_in, const int* in_sizes, int n_in,
                              void* d_out, int out_size, void* d_ws, size_t ws_size,
                              hipStream_t stream) {
  const float* xf  = (const float*)d_in[0];
  const float* wqf = (const float*)d_in[1];
  const float* wkf = (const float*)d_in[2];
  const float* wvf = (const float*)d_in[3];
  const float* wof = (const float*)d_in[4];
  float* out = (float*)d_out;
  unsigned short* ws = (unsigned short*)d_ws;

  const bool fused = ws_size >= (size_t)58720256;  // 56 MB

  if (fused) {
    unsigned short* xb  = ws;                    // 8M elems; aliased by Ow after qkv
    unsigned short* wb  = ws + 8388608;          // wq|wk|wv|wo, 1M each
    unsigned short* Kw  = ws + 12582912;
    unsigned short* Vw  = ws + 20971520;
    unsigned short* Ow  = xb;
    unsigned short* Qd  = (unsigned short*)out;  // bf16 Q scratch in fp32 out region

    cvt_kernel <<<2048, 256, 0, stream>>>(xf, xb, 8388608/4);
    cvt4_kernel<<<dim3(256, 4), 256, 0, stream>>>(wqf, wkf, wvf, wof, wb);

    qkv_kernel <<<dim3(64, 8, 3), 256, 0, stream>>>(xb, wb, wb + 1048576, wb + 2097152,
                                                    Qd, Kw, Vw);
    attn_kernel<<<dim3(64, 8),    256, 0, stream>>>(Qd, Kw, Vw, Ow);
    proj_kernel<<<dim3(64, 8),    256, 0, stream>>>(Ow, wb + 3145728, out);
  } else {
    unsigned short* xb  = ws;
    unsigned short* wb  = ws + 8388608;
    unsigned short* Kw  = ws + 12582912;
    unsigned short* Vw  = ws + 14680064;
    unsigned short* Ow  = ws + 16777216;

    cvt_kernel <<<2048, 256, 0, stream>>>(xf, xb, 8388608/4);
    cvt4_kernel<<<dim3(256, 4), 256, 0, stream>>>(wqf, wkf, wvf, wof, wb);

    for (int b = 0; b < 4; ++b) {
      const unsigned short* xbb = xb  + (size_t)b * 2048 * 1024;
      float*               outb = out + (size_t)b * 2048 * 1024;
      unsigned short*        Qd = (unsigned short*)outb;
      qkv_kernel <<<dim3(16, 8, 3), 256, 0, stream>>>(xbb, wb, wb + 1048576, wb + 2097152,
                                                      Qd, Kw, Vw);
      attn_kernel<<<dim3(16, 8),    256, 0, stream>>>(Qd, Kw, Vw, Ow);
      proj_kernel<<<dim3(16, 8),    256, 0, stream>>>(Ow, wb + 3145728, outb);
    }
  }
}